// Round 1
// baseline (3836.280 us; speedup 1.0000x reference)
//
#include <hip/hip_runtime.h>
#include <math.h>

// Problem constants
#define DD    64          // feature dim
#define TT    256         // timesteps
#define NROW  4096        // B*C rows
#define ROWS  16          // rows per block
#define BLK   256         // threads per block
#define SROW  68          // padded row stride (floats) for s/x/msg tiles (16B-aligned, 2-way banks)
#define WMROW 132         // msg_W padded row stride (128 used + 4 pad)
#define WROW  68          // W_ih / W_hh padded row stride (64 used + 4 pad)

// LDS layout (float offsets)
#define OFF_WM 0
#define OFF_WI (OFF_WM + 64*WMROW)        // 8448
#define OFF_WH (OFF_WI + 192*WROW)        // 21504
#define OFF_S  (OFF_WH + 192*WROW)        // 34560
#define OFF_X  (OFF_S  + ROWS*SROW)       // 35648
#define OFF_M  (OFF_X  + ROWS*SROW)       // 36736
#define SMEM_FLOATS (OFF_M + ROWS*SROW)   // 37824 floats = 151296 B

// Precompute per-timestep msg bias: bias_t[t][j] = msg_b[j] + sum_d cos(t*freq[d]+phase[d]) * msg_W[j][128+d]
__global__ void bias_kernel(const float* __restrict__ msg_W,
                            const float* __restrict__ msg_b,
                            const float* __restrict__ freq,
                            const float* __restrict__ phase,
                            float* __restrict__ bias_t) {
  __shared__ float teL[DD];
  const int t = blockIdx.x;
  const int j = threadIdx.x;
  teL[j] = cosf(fmaf((float)t, freq[j], phase[j]));
  __syncthreads();
  float acc = msg_b[j];
  const float* wrow = msg_W + j * 192 + 128;
  #pragma unroll 8
  for (int k = 0; k < DD; ++k) acc = fmaf(teL[k], wrow[k], acc);
  bias_t[t * DD + j] = acc;
}

__launch_bounds__(BLK, 1)
__global__ void scan_kernel(const float* __restrict__ x,
                            const int*   __restrict__ mask,
                            const float* __restrict__ msg_W,
                            const float* __restrict__ W_ih,
                            const float* __restrict__ W_hh,
                            const float* __restrict__ b_ih,
                            const float* __restrict__ b_hh,
                            const float* __restrict__ bias_t,
                            float* __restrict__ out) {
  extern __shared__ float sm[];
  const int tid  = threadIdx.x;
  const int r    = tid & 15;        // row within tile
  const int g    = tid >> 4;        // output-slice group (0..15)
  const int row0 = blockIdx.x * ROWS;
  const int row  = row0 + r;

  // ---- stage weights into LDS (once) ----
  for (int idx = tid; idx < 64 * 128; idx += BLK) {
    int j = idx >> 7, k = idx & 127;
    sm[OFF_WM + j * WMROW + k] = msg_W[j * 192 + k];  // x-part k<64, s-part 64<=k<128
  }
  for (int idx = tid; idx < 192 * 64; idx += BLK) {
    int q = idx >> 6, k = idx & 63;
    sm[OFF_WI + q * WROW + k] = W_ih[q * 64 + k];
    sm[OFF_WH + q * WROW + k] = W_hh[q * 64 + k];
  }

  // ---- gate biases to registers (thread owns q = p*64 + g*4 + u) ----
  float bih[3][4], bhh[3][4];
  #pragma unroll
  for (int p = 0; p < 3; ++p)
    #pragma unroll
    for (int u = 0; u < 4; ++u) {
      int q = p * 64 + g * 4 + u;
      bih[p][u] = b_ih[q];
      bhh[p][u] = b_hh[q];
    }

  // ---- s0 = mean over t of x[:, row, g*4..g*4+3] ----
  {
    float ax = 0.f, ay = 0.f, az = 0.f, aw = 0.f;
    const float* px = x + (size_t)row * DD + g * 4;
    #pragma unroll 4
    for (int t = 0; t < TT; ++t) {
      float4 v = *(const float4*)(px + (size_t)t * (NROW * DD));
      ax += v.x; ay += v.y; az += v.z; aw += v.w;
    }
    const float inv = 1.0f / 256.0f;
    float* ps = &sm[OFF_S + r * SROW + g * 4];
    ps[0] = ax * inv; ps[1] = ay * inv; ps[2] = az * inv; ps[3] = aw * inv;
  }

  // linear f = tid*4 mapping for coalesced tile load/store
  const int fr = tid >> 4;          // row index for linear tile access
  const int fd = (tid & 15) * 4;    // dword4 offset within row

  // preload x tile for t=0 (t_idx = 0*mask[0] = 0 always)
  float4 xv = *(const float4*)(x + ((size_t)(row0 + fr)) * DD + fd);

  __syncthreads();  // weights + s0 visible

  int tcur_idx = 0; // t_idx for t=0

  for (int t = 0; t < TT; ++t) {
    // stage current x tile (prev-step readers finished at S2 of t-1)
    *(float4*)&sm[OFF_X + fr * SROW + fd] = xv;
    int tn = 0;
    if (t + 1 < TT) tn = (t + 1) * mask[t + 1];
    __syncthreads();  // S1: x tile ready

    // prefetch next x tile (consumed at next loop top — full step of latency cover)
    if (t + 1 < TT)
      xv = *(const float4*)(x + ((size_t)tn * NROW + row0 + fr) * DD + fd);
    // per-t msg bias (L2-hot), added at end of accumulation
    float4 bt = *(const float4*)(bias_t + tcur_idx * DD + g * 4);

    // ---- Phase A/B: msg pre-act (x-part + s-part) and gh = s @ W_hh^T ----
    float accm[4] = {0.f, 0.f, 0.f, 0.f};
    float acch[3][4];
    #pragma unroll
    for (int p = 0; p < 3; ++p)
      #pragma unroll
      for (int u = 0; u < 4; ++u) acch[p][u] = 0.f;

    const float* sr = &sm[OFF_S + r * SROW];
    const float* xr = &sm[OFF_X + r * SROW];
    #pragma unroll 4
    for (int k4 = 0; k4 < 16; ++k4) {
      float4 skv = *(const float4*)(sr + k4 * 4);
      float4 xkv = *(const float4*)(xr + k4 * 4);
      #pragma unroll
      for (int u = 0; u < 4; ++u) {
        const float* wm = &sm[OFF_WM + (g * 4 + u) * WMROW];
        float4 wx = *(const float4*)(wm + k4 * 4);
        float4 ws = *(const float4*)(wm + 64 + k4 * 4);
        float a = accm[u];
        a = fmaf(xkv.x, wx.x, a); a = fmaf(xkv.y, wx.y, a);
        a = fmaf(xkv.z, wx.z, a); a = fmaf(xkv.w, wx.w, a);
        a = fmaf(skv.x, ws.x, a); a = fmaf(skv.y, ws.y, a);
        a = fmaf(skv.z, ws.z, a); a = fmaf(skv.w, ws.w, a);
        accm[u] = a;
      }
      #pragma unroll
      for (int p = 0; p < 3; ++p)
        #pragma unroll
        for (int u = 0; u < 4; ++u) {
          float4 wh = *(const float4*)&sm[OFF_WH + (p * 64 + g * 4 + u) * WROW + k4 * 4];
          float a = acch[p][u];
          a = fmaf(skv.x, wh.x, a); a = fmaf(skv.y, wh.y, a);
          a = fmaf(skv.z, wh.z, a); a = fmaf(skv.w, wh.w, a);
          acch[p][u] = a;
        }
    }

    // GELU (exact, erf) -> msg tile
    {
      const float btv[4] = {bt.x, bt.y, bt.z, bt.w};
      #pragma unroll
      for (int u = 0; u < 4; ++u) {
        float a = accm[u] + btv[u];
        float mgv = 0.5f * a * (1.0f + erff(a * 0.70710678118654752f));
        sm[OFF_M + r * SROW + g * 4 + u] = mgv;
      }
    }
    __syncthreads();  // S2: msg ready; all s reads of phase A done

    // ---- Phase C: gi = msg @ W_ih^T ----
    float acci[3][4];
    #pragma unroll
    for (int p = 0; p < 3; ++p)
      #pragma unroll
      for (int u = 0; u < 4; ++u) acci[p][u] = 0.f;

    const float* mr = &sm[OFF_M + r * SROW];
    #pragma unroll 4
    for (int k4 = 0; k4 < 16; ++k4) {
      float4 mk = *(const float4*)(mr + k4 * 4);
      #pragma unroll
      for (int p = 0; p < 3; ++p)
        #pragma unroll
        for (int u = 0; u < 4; ++u) {
          float4 wi = *(const float4*)&sm[OFF_WI + (p * 64 + g * 4 + u) * WROW + k4 * 4];
          float a = acci[p][u];
          a = fmaf(mk.x, wi.x, a); a = fmaf(mk.y, wi.y, a);
          a = fmaf(mk.z, wi.z, a); a = fmaf(mk.w, wi.w, a);
          acci[p][u] = a;
        }
    }

    // ---- Phase D: gates (torch order r,z,n) + state update ----
    float snew[4];
    #pragma unroll
    for (int u = 0; u < 4; ++u) {
      float gr = acci[0][u] + bih[0][u] + acch[0][u] + bhh[0][u];
      float gz = acci[1][u] + bih[1][u] + acch[1][u] + bhh[1][u];
      float gni = acci[2][u] + bih[2][u];
      float gnh = acch[2][u] + bhh[2][u];
      float rg = 1.0f / (1.0f + expf(-gr));
      float zg = 1.0f / (1.0f + expf(-gz));
      float ng = tanhf(fmaf(rg, gnh, gni));
      float so = sm[OFF_S + r * SROW + g * 4 + u];  // thread-private element
      snew[u] = fmaf(zg, so - ng, ng);              // (1-z)*n + z*s
    }
    #pragma unroll
    for (int u = 0; u < 4; ++u) sm[OFF_S + r * SROW + g * 4 + u] = snew[u];
    __syncthreads();  // S3: s fully updated

    // coalesced output write from the state tile
    {
      float4 ov = *(const float4*)&sm[OFF_S + fr * SROW + fd];
      *(float4*)(out + ((size_t)t * NROW + row0 + fr) * DD + fd) = ov;
    }

    // t_idx for next iteration's bias lookup
    tcur_idx = tn;
  }
}

extern "C" void kernel_launch(void* const* d_in, const int* in_sizes, int n_in,
                              void* d_out, int out_size, void* d_ws, size_t ws_size,
                              hipStream_t stream) {
  const float* x      = (const float*)d_in[0];
  const int*   mask   = (const int*)  d_in[1];
  const float* msg_W  = (const float*)d_in[2];
  const float* msg_b  = (const float*)d_in[3];
  const float* W_ih   = (const float*)d_in[4];
  const float* W_hh   = (const float*)d_in[5];
  const float* b_ih   = (const float*)d_in[6];
  const float* b_hh   = (const float*)d_in[7];
  const float* freq   = (const float*)d_in[8];
  const float* phase  = (const float*)d_in[9];
  float* out = (float*)d_out;
  float* bias_t = (float*)d_ws;   // TT*DD floats = 64 KB

  (void)in_sizes; (void)n_in; (void)out_size; (void)ws_size;

  static bool attr_set = false;
  // hipFuncSetAttribute is idempotent and not a stream op; safe under graph capture.
  hipFuncSetAttribute((const void*)scan_kernel,
                      hipFuncAttributeMaxDynamicSharedMemorySize,
                      SMEM_FLOATS * (int)sizeof(float));
  (void)attr_set;

  bias_kernel<<<TT, DD, 0, stream>>>(msg_W, msg_b, freq, phase, bias_t);
  scan_kernel<<<NROW / ROWS, BLK, SMEM_FLOATS * sizeof(float), stream>>>(
      x, mask, msg_W, W_ih, W_hh, b_ih, b_hh, bias_t, out);
}

// Round 2
// 583.541 us; speedup vs baseline: 6.5741x; 6.5741x over previous
//
#include <hip/hip_runtime.h>
#include <math.h>

#define DD    64
#define TT    256
#define NROW  4096
#define ROWS  16
#define BLK   256

typedef __attribute__((ext_vector_type(8))) short  short8;
typedef __attribute__((ext_vector_type(4))) float  f32x4;

__device__ __forceinline__ unsigned short f2bf(float f) {
  unsigned u = __builtin_bit_cast(unsigned, f);
  u += 0x7fffu + ((u >> 16) & 1u);          // round-to-nearest-even
  return (unsigned short)(u >> 16);
}

__device__ __forceinline__ unsigned long long pack4(float4 v) {
  return (unsigned long long)f2bf(v.x)
       | ((unsigned long long)f2bf(v.y) << 16)
       | ((unsigned long long)f2bf(v.z) << 32)
       | ((unsigned long long)f2bf(v.w) << 48);
}

__device__ __forceinline__ short8 load_wfrag(const float* p) {
  float4 a = *(const float4*)p;
  float4 b = *(const float4*)(p + 4);
  short8 r;
  r[0] = (short)f2bf(a.x); r[1] = (short)f2bf(a.y);
  r[2] = (short)f2bf(a.z); r[3] = (short)f2bf(a.w);
  r[4] = (short)f2bf(b.x); r[5] = (short)f2bf(b.y);
  r[6] = (short)f2bf(b.z); r[7] = (short)f2bf(b.w);
  return r;
}

// bias_t[t][j] = msg_b[j] + sum_d cos(t*freq[d]+phase[d]) * msg_W[j][128+d]
__global__ void bias_kernel(const float* __restrict__ msg_W,
                            const float* __restrict__ msg_b,
                            const float* __restrict__ freq,
                            const float* __restrict__ phase,
                            float* __restrict__ bias_t) {
  __shared__ float teL[DD];
  const int t = blockIdx.x;
  const int j = threadIdx.x;
  teL[j] = cosf(fmaf((float)t, freq[j], phase[j]));
  __syncthreads();
  float acc = msg_b[j];
  const float* wrow = msg_W + j * 192 + 128;
  #pragma unroll 8
  for (int k = 0; k < DD; ++k) acc = fmaf(teL[k], wrow[k], acc);
  bias_t[t * DD + j] = acc;
}

__launch_bounds__(BLK)
__global__ void scan2(const float* __restrict__ x,
                      const int*   __restrict__ mask,
                      const float* __restrict__ msg_W,
                      const float* __restrict__ W_ih,
                      const float* __restrict__ W_hh,
                      const float* __restrict__ b_ih,
                      const float* __restrict__ b_hh,
                      const float* __restrict__ bias_t,
                      float* __restrict__ out) {
  // bf16 tiles: stride 72 shorts (144 B) -> 2-way banks max on b128 frag reads
  __shared__ alignas(16) unsigned short xs[ROWS * 72];
  __shared__ alignas(16) unsigned short ss[ROWS * 72];
  __shared__ alignas(16) unsigned short ms[ROWS * 72];
  __shared__ alignas(16) float          sf[ROWS * 68];   // fp32 state

  const int tid  = threadIdx.x;
  const int lane = tid & 63;
  const int w    = tid >> 6;          // wave id: owns output cols [16w,16w+16)
  const int col  = lane & 15;
  const int kh   = lane >> 4;         // k-group for A/B frags, row-group for C
  const int n    = w * 16 + col;      // output column this lane owns
  const int row0 = blockIdx.x * ROWS;

  // ---- weight B-fragments in registers (one-time) ----
  short8 wm[4], wh[3][2], wi[3][2];
  {
    const float* mrow = msg_W + (size_t)n * 192;
    #pragma unroll
    for (int kf = 0; kf < 4; ++kf) wm[kf] = load_wfrag(mrow + kf * 32 + kh * 8);
    #pragma unroll
    for (int p = 0; p < 3; ++p) {
      const float* hrow = W_hh + (size_t)(p * 64 + n) * 64;
      const float* irow = W_ih + (size_t)(p * 64 + n) * 64;
      #pragma unroll
      for (int kf = 0; kf < 2; ++kf) {
        wh[p][kf] = load_wfrag(hrow + kf * 32 + kh * 8);
        wi[p][kf] = load_wfrag(irow + kf * 32 + kh * 8);
      }
    }
  }
  float bihr[3], bhhr[3];
  #pragma unroll
  for (int p = 0; p < 3; ++p) { bihr[p] = b_ih[p * 64 + n]; bhhr[p] = b_hh[p * 64 + n]; }

  // linear mapping for coalesced staging / output
  const int fr = tid >> 4;
  const int fd = (tid & 15) * 4;

  // ---- s0 = mean over t; stage x tile for t=0 (t_idx = 0) ----
  {
    const float* px = x + (size_t)(row0 + fr) * DD + fd;
    float4 acc = {0.f, 0.f, 0.f, 0.f};
    #pragma unroll 4
    for (int t = 0; t < TT; ++t) {
      float4 v = *(const float4*)(px + (size_t)t * (NROW * DD));
      acc.x += v.x; acc.y += v.y; acc.z += v.z; acc.w += v.w;
    }
    const float inv = 1.0f / 256.0f;
    acc.x *= inv; acc.y *= inv; acc.z *= inv; acc.w *= inv;
    *(float4*)&sf[fr * 68 + fd] = acc;
    *(unsigned long long*)&ss[fr * 72 + fd] = pack4(acc);
    float4 xv = *(const float4*)px;   // t_idx 0
    *(unsigned long long*)&xs[fr * 72 + fd] = pack4(xv);
  }
  __syncthreads();

  int tidx = 0;  // gathered time index for current step
  for (int t = 0; t < TT; ++t) {
    // ---- A-fragments (row = lane&15, k = kh*8 + [0..7] within 32-k frag) ----
    const unsigned short* arow_x = &xs[(lane & 15) * 72];
    const unsigned short* arow_s = &ss[(lane & 15) * 72];
    short8 xa0 = *(const short8*)(arow_x + kh * 8);
    short8 xa1 = *(const short8*)(arow_x + 32 + kh * 8);
    short8 sa0 = *(const short8*)(arow_s + kh * 8);
    short8 sa1 = *(const short8*)(arow_s + 32 + kh * 8);

    // msg pre-act: [x | s] (16x128) @ msg_W12^T slice
    f32x4 accm = {0.f, 0.f, 0.f, 0.f};
    accm = __builtin_amdgcn_mfma_f32_16x16x32_bf16(xa0, wm[0], accm, 0, 0, 0);
    accm = __builtin_amdgcn_mfma_f32_16x16x32_bf16(xa1, wm[1], accm, 0, 0, 0);
    accm = __builtin_amdgcn_mfma_f32_16x16x32_bf16(sa0, wm[2], accm, 0, 0, 0);
    accm = __builtin_amdgcn_mfma_f32_16x16x32_bf16(sa1, wm[3], accm, 0, 0, 0);
    // gh = s @ W_hh^T slices (r,z,n)
    f32x4 agh[3];
    #pragma unroll
    for (int p = 0; p < 3; ++p) {
      f32x4 c = {0.f, 0.f, 0.f, 0.f};
      c = __builtin_amdgcn_mfma_f32_16x16x32_bf16(sa0, wh[p][0], c, 0, 0, 0);
      c = __builtin_amdgcn_mfma_f32_16x16x32_bf16(sa1, wh[p][1], c, 0, 0, 0);
      agh[p] = c;
    }

    // prefetch next x tile + gathered index
    int tn = 0;
    float4 xv = {0.f, 0.f, 0.f, 0.f};
    if (t + 1 < TT) {
      tn = (t + 1) * mask[t + 1];
      xv = *(const float4*)(x + ((size_t)tn * NROW + row0 + fr) * DD + fd);
    }
    float bt = bias_t[tidx * DD + n];

    // GELU (exact erf) -> msg tile (bf16)
    #pragma unroll
    for (int i = 0; i < 4; ++i) {
      float a = accm[i] + bt;
      float g = 0.5f * a * (1.0f + erff(a * 0.70710678118654752f));
      ms[(kh * 4 + i) * 72 + n] = f2bf(g);
    }
    __syncthreads();  // S1: msg visible; all ss/xs reads of this step done

    // gi = msg @ W_ih^T slices
    const unsigned short* arow_m = &ms[(lane & 15) * 72];
    short8 ma0 = *(const short8*)(arow_m + kh * 8);
    short8 ma1 = *(const short8*)(arow_m + 32 + kh * 8);
    f32x4 agi[3];
    #pragma unroll
    for (int p = 0; p < 3; ++p) {
      f32x4 c = {0.f, 0.f, 0.f, 0.f};
      c = __builtin_amdgcn_mfma_f32_16x16x32_bf16(ma0, wi[p][0], c, 0, 0, 0);
      c = __builtin_amdgcn_mfma_f32_16x16x32_bf16(ma1, wi[p][1], c, 0, 0, 0);
      agi[p] = c;
    }

    // gates (torch order r,z,n) + state update; C-frag: row = kh*4+i, col = n
    #pragma unroll
    for (int i = 0; i < 4; ++i) {
      const int rr = kh * 4 + i;
      float gr  = agi[0][i] + bihr[0] + agh[0][i] + bhhr[0];
      float gz  = agi[1][i] + bihr[1] + agh[1][i] + bhhr[1];
      float gni = agi[2][i] + bihr[2];
      float gnh = agh[2][i] + bhhr[2];
      float rg = 1.0f / (1.0f + expf(-gr));
      float zg = 1.0f / (1.0f + expf(-gz));
      float ng = tanhf(fmaf(rg, gnh, gni));
      float so = sf[rr * 68 + n];
      float sn = fmaf(zg, so - ng, ng);
      sf[rr * 68 + n] = sn;
      ss[rr * 72 + n] = f2bf(sn);
    }
    // stage x for t+1 (xs reads for step t all happened before S1)
    if (t + 1 < TT) *(unsigned long long*)&xs[fr * 72 + fd] = pack4(xv);
    __syncthreads();  // S2: sf/ss/xs updated

    // coalesced output write from fp32 state tile
    float4 ov = *(const float4*)&sf[fr * 68 + fd];
    *(float4*)(out + ((size_t)t * NROW + row0 + fr) * DD + fd) = ov;

    tidx = tn;
  }
}

extern "C" void kernel_launch(void* const* d_in, const int* in_sizes, int n_in,
                              void* d_out, int out_size, void* d_ws, size_t ws_size,
                              hipStream_t stream) {
  const float* x      = (const float*)d_in[0];
  const int*   mask   = (const int*)  d_in[1];
  const float* msg_W  = (const float*)d_in[2];
  const float* msg_b  = (const float*)d_in[3];
  const float* W_ih   = (const float*)d_in[4];
  const float* W_hh   = (const float*)d_in[5];
  const float* b_ih   = (const float*)d_in[6];
  const float* b_hh   = (const float*)d_in[7];
  const float* freq   = (const float*)d_in[8];
  const float* phase  = (const float*)d_in[9];
  float* out    = (float*)d_out;
  float* bias_t = (float*)d_ws;   // TT*DD floats = 64 KB

  (void)in_sizes; (void)n_in; (void)out_size; (void)ws_size;

  bias_kernel<<<TT, DD, 0, stream>>>(msg_W, msg_b, freq, phase, bias_t);
  scan2<<<NROW / ROWS, BLK, 0, stream>>>(x, mask, msg_W, W_ih, W_hh,
                                         b_ih, b_hh, bias_t, out);
}

// Round 3
// 413.417 us; speedup vs baseline: 9.2794x; 1.4115x over previous
//
#include <hip/hip_runtime.h>
#include <math.h>

#define DD    64
#define TT    256
#define NROW  4096
#define ROWS  8            // valid rows per block (MFMA tile rows 8..15 are garbage)
#define BLK   256
#define GRID  (NROW / ROWS)   // 512 blocks -> 2 blocks/CU -> 2 waves/SIMD

typedef __attribute__((ext_vector_type(8))) short  short8;
typedef __attribute__((ext_vector_type(4))) float  f32x4;

__device__ __forceinline__ unsigned short f2bf(float f) {
  unsigned u = __builtin_bit_cast(unsigned, f);
  u += 0x7fffu + ((u >> 16) & 1u);          // round-to-nearest-even
  return (unsigned short)(u >> 16);
}

__device__ __forceinline__ unsigned long long pack4(float4 v) {
  return (unsigned long long)f2bf(v.x)
       | ((unsigned long long)f2bf(v.y) << 16)
       | ((unsigned long long)f2bf(v.z) << 32)
       | ((unsigned long long)f2bf(v.w) << 48);
}

__device__ __forceinline__ short8 load_wfrag(const float* p) {
  float4 a = *(const float4*)p;
  float4 b = *(const float4*)(p + 4);
  short8 r;
  r[0] = (short)f2bf(a.x); r[1] = (short)f2bf(a.y);
  r[2] = (short)f2bf(a.z); r[3] = (short)f2bf(a.w);
  r[4] = (short)f2bf(b.x); r[5] = (short)f2bf(b.y);
  r[6] = (short)f2bf(b.z); r[7] = (short)f2bf(b.w);
  return r;
}

// fast sigmoid / tanh via v_exp_f32; rel err ~1e-6 (negligible vs bf16 path)
__device__ __forceinline__ float fsigmoid(float x) {
  return __builtin_amdgcn_rcpf(1.0f + __expf(-x));
}
__device__ __forceinline__ float ftanh(float x) {
  return 1.0f - 2.0f * __builtin_amdgcn_rcpf(1.0f + __expf(2.0f * x));
}
// A&S 7.1.26 erf, max abs err 1.5e-7
__device__ __forceinline__ float ferf(float x) {
  float ax = fabsf(x);
  float t  = __builtin_amdgcn_rcpf(fmaf(0.3275911f, ax, 1.0f));
  float p  = fmaf(1.061405429f, t, -1.453152027f);
  p = fmaf(p, t, 1.421413741f);
  p = fmaf(p, t, -0.284496736f);
  p = fmaf(p, t, 0.254829592f);
  p = p * t;
  float y = 1.0f - p * __expf(-ax * ax);
  return copysignf(y, x);
}

// bias_t[t][j] = msg_b[j] + sum_d cos(t*freq[d]+phase[d]) * msg_W[j][128+d]
__global__ void bias_kernel(const float* __restrict__ msg_W,
                            const float* __restrict__ msg_b,
                            const float* __restrict__ freq,
                            const float* __restrict__ phase,
                            float* __restrict__ bias_t) {
  __shared__ float teL[DD];
  const int t = blockIdx.x;
  const int j = threadIdx.x;
  teL[j] = cosf(fmaf((float)t, freq[j], phase[j]));
  __syncthreads();
  float acc = msg_b[j];
  const float* wrow = msg_W + j * 192 + 128;
  #pragma unroll 8
  for (int k = 0; k < DD; ++k) acc = fmaf(teL[k], wrow[k], acc);
  bias_t[t * DD + j] = acc;
}

__launch_bounds__(BLK, 2)
__global__ void scan3(const float* __restrict__ x,
                      const int*   __restrict__ mask,
                      const float* __restrict__ msg_W,
                      const float* __restrict__ W_ih,
                      const float* __restrict__ W_hh,
                      const float* __restrict__ b_ih,
                      const float* __restrict__ b_hh,
                      const float* __restrict__ bias_t,
                      float* __restrict__ out) {
  // bf16 tiles, stride 72 shorts (144 B): 16B-aligned rows, <=2-way banks (free)
  __shared__ alignas(16) unsigned short xs[16 * 72];
  __shared__ alignas(16) unsigned short ss[16 * 72];
  __shared__ alignas(16) unsigned short ms[16 * 72];
  __shared__ alignas(16) float          s0a[16 * 68];  // scratch: s0 partials, then out-staging
  __shared__ int tr_lds[TT];

  const int tid  = threadIdx.x;
  const int lane = tid & 63;
  const int w    = tid >> 6;          // wave id: owns output cols [16w,16w+16)
  const int col  = lane & 15;
  const int kh   = lane >> 4;         // k-group for A/B frags, row-group for C
  const int n    = w * 16 + col;      // output column this lane owns
  const int row0 = blockIdx.x * ROWS;

  // ---- weight B-fragments in registers (one-time) ----
  short8 wm[4], wh[3][2], wi[3][2];
  {
    const float* mrow = msg_W + (size_t)n * 192;
    #pragma unroll
    for (int kf = 0; kf < 4; ++kf) wm[kf] = load_wfrag(mrow + kf * 32 + kh * 8);
    #pragma unroll
    for (int p = 0; p < 3; ++p) {
      const float* hrow = W_hh + (size_t)(p * 64 + n) * 64;
      const float* irow = W_ih + (size_t)(p * 64 + n) * 64;
      #pragma unroll
      for (int kf = 0; kf < 2; ++kf) {
        wh[p][kf] = load_wfrag(hrow + kf * 32 + kh * 8);
        wi[p][kf] = load_wfrag(irow + kf * 32 + kh * 8);
      }
    }
  }
  float bihr[3], bhhr[3];
  #pragma unroll
  for (int p = 0; p < 3; ++p) { bihr[p] = b_ih[p * 64 + n]; bhhr[p] = b_hh[p * 64 + n]; }

  // gather index table: tr[t] = t * mask[t]
  tr_lds[tid] = tid * mask[tid];

  // linear staging map: threads 0..127 cover 8 rows x 16 float4
  const int half = tid >> 7;          // 0/1: time-half for s0 mean
  const int fr   = (tid >> 4) & 7;    // row 0..7
  const int fd   = (tid & 15) * 4;    // float4 offset

  // ---- s0 = mean over t (time-split across thread halves) ----
  {
    const float* px = x + ((size_t)half * 128) * (NROW * DD)
                        + (size_t)(row0 + fr) * DD + fd;
    float4 acc = {0.f, 0.f, 0.f, 0.f};
    #pragma unroll 4
    for (int tl = 0; tl < 128; ++tl) {
      float4 v = *(const float4*)(px + (size_t)tl * (NROW * DD));
      acc.x += v.x; acc.y += v.y; acc.z += v.z; acc.w += v.w;
    }
    *(float4*)&s0a[(half * 8 + fr) * 68 + fd] = acc;
  }
  __syncthreads();
  if (tid < 128) {
    float4 a = *(const float4*)&s0a[fr * 68 + fd];
    float4 b = *(const float4*)&s0a[(8 + fr) * 68 + fd];
    const float inv = 1.0f / 256.0f;
    float4 m = { (a.x + b.x) * inv, (a.y + b.y) * inv,
                 (a.z + b.z) * inv, (a.w + b.w) * inv };
    *(float4*)&s0a[fr * 68 + fd] = m;                 // fp32 s0 (read by gate lanes)
    *(unsigned long long*)&ss[fr * 72 + fd] = pack4(m);
    // stage x tile for t=0 (tr[0] == 0 always)
    float4 xv0 = *(const float4*)(x + (size_t)(row0 + fr) * DD + fd);
    *(unsigned long long*)&xs[fr * 72 + fd] = pack4(xv0);
  }
  __syncthreads();

  // per-lane fp32 state registers: lane owns (rr = kh*4+i, n)
  float s_reg[4];
  #pragma unroll
  for (int i = 0; i < 4; ++i) s_reg[i] = s0a[(kh * 4 + i) * 68 + n];

  float btc = bias_t[n];   // bias for t=0 (tr[0]=0)
  float4 xv = {0.f, 0.f, 0.f, 0.f};

  for (int t = 0; t < TT; ++t) {
    // ---- A-fragments (row = lane&15, k = kh*8 within each 32-k frag) ----
    const unsigned short* arow_x = &xs[(lane & 15) * 72];
    const unsigned short* arow_s = &ss[(lane & 15) * 72];
    short8 xa0 = *(const short8*)(arow_x + kh * 8);
    short8 xa1 = *(const short8*)(arow_x + 32 + kh * 8);
    short8 sa0 = *(const short8*)(arow_s + kh * 8);
    short8 sa1 = *(const short8*)(arow_s + 32 + kh * 8);

    f32x4 accm = {0.f, 0.f, 0.f, 0.f};
    accm = __builtin_amdgcn_mfma_f32_16x16x32_bf16(xa0, wm[0], accm, 0, 0, 0);
    accm = __builtin_amdgcn_mfma_f32_16x16x32_bf16(xa1, wm[1], accm, 0, 0, 0);
    accm = __builtin_amdgcn_mfma_f32_16x16x32_bf16(sa0, wm[2], accm, 0, 0, 0);
    accm = __builtin_amdgcn_mfma_f32_16x16x32_bf16(sa1, wm[3], accm, 0, 0, 0);
    f32x4 agh[3];
    #pragma unroll
    for (int p = 0; p < 3; ++p) {
      f32x4 c = {0.f, 0.f, 0.f, 0.f};
      c = __builtin_amdgcn_mfma_f32_16x16x32_bf16(sa0, wh[p][0], c, 0, 0, 0);
      c = __builtin_amdgcn_mfma_f32_16x16x32_bf16(sa1, wh[p][1], c, 0, 0, 0);
      agh[p] = c;
    }

    // prefetch next step's x tile, gather index, and msg bias
    int tn = 0; float btn = 0.0f;
    if (t + 1 < TT) {
      tn  = tr_lds[t + 1];
      btn = bias_t[tn * DD + n];
      if (tid < 128)
        xv = *(const float4*)(x + ((size_t)tn * NROW + row0 + fr) * DD + fd);
    }

    // GELU (fast erf) -> msg tile (bf16)
    #pragma unroll
    for (int i = 0; i < 4; ++i) {
      float a = accm[i] + btc;
      float g = 0.5f * a * (1.0f + ferf(a * 0.70710678118654752f));
      ms[(kh * 4 + i) * 72 + n] = f2bf(g);
    }
    __syncthreads();  // S1: msg visible; xs/ss reads of this step done

    // gi = msg @ W_ih^T slices
    const unsigned short* arow_m = &ms[(lane & 15) * 72];
    short8 ma0 = *(const short8*)(arow_m + kh * 8);
    short8 ma1 = *(const short8*)(arow_m + 32 + kh * 8);
    f32x4 agi[3];
    #pragma unroll
    for (int p = 0; p < 3; ++p) {
      f32x4 c = {0.f, 0.f, 0.f, 0.f};
      c = __builtin_amdgcn_mfma_f32_16x16x32_bf16(ma0, wi[p][0], c, 0, 0, 0);
      c = __builtin_amdgcn_mfma_f32_16x16x32_bf16(ma1, wi[p][1], c, 0, 0, 0);
      agi[p] = c;
    }

    // gates (torch order r,z,n) + state update; lane owns (rr = kh*4+i, n)
    #pragma unroll
    for (int i = 0; i < 4; ++i) {
      const int rr = kh * 4 + i;
      float gr  = agi[0][i] + bihr[0] + agh[0][i] + bhhr[0];
      float gz  = agi[1][i] + bihr[1] + agh[1][i] + bhhr[1];
      float gni = agi[2][i] + bihr[2];
      float gnh = agh[2][i] + bhhr[2];
      float rg = fsigmoid(gr);
      float zg = fsigmoid(gz);
      float ng = ftanh(fmaf(rg, gnh, gni));
      float sn = fmaf(zg, s_reg[i] - ng, ng);
      s_reg[i] = sn;
      ss[rr * 72 + n]  = f2bf(sn);
      s0a[rr * 68 + n] = sn;            // fp32 staging for coalesced out-write
    }
    // stage x for t+1 (xs reads of step t finished before S1)
    if (t + 1 < TT && tid < 128)
      *(unsigned long long*)&xs[fr * 72 + fd] = pack4(xv);
    __syncthreads();  // S2: ss/xs/s0a updated

    // coalesced output write (valid rows only)
    if (tid < 128) {
      float4 ov = *(const float4*)&s0a[fr * 68 + fd];
      *(float4*)(out + ((size_t)t * NROW + row0 + fr) * DD + fd) = ov;
    }

    btc = btn;
  }
}

extern "C" void kernel_launch(void* const* d_in, const int* in_sizes, int n_in,
                              void* d_out, int out_size, void* d_ws, size_t ws_size,
                              hipStream_t stream) {
  const float* x      = (const float*)d_in[0];
  const int*   mask   = (const int*)  d_in[1];
  const float* msg_W  = (const float*)d_in[2];
  const float* msg_b  = (const float*)d_in[3];
  const float* W_ih   = (const float*)d_in[4];
  const float* W_hh   = (const float*)d_in[5];
  const float* b_ih   = (const float*)d_in[6];
  const float* b_hh   = (const float*)d_in[7];
  const float* freq   = (const float*)d_in[8];
  const float* phase  = (const float*)d_in[9];
  float* out    = (float*)d_out;
  float* bias_t = (float*)d_ws;   // TT*DD floats = 64 KB

  (void)in_sizes; (void)n_in; (void)out_size; (void)ws_size;

  bias_kernel<<<TT, DD, 0, stream>>>(msg_W, msg_b, freq, phase, bias_t);
  scan3<<<GRID, BLK, 0, stream>>>(x, mask, msg_W, W_ih, W_hh,
                                  b_ih, b_hh, bias_t, out);
}

// Round 4
// 305.170 us; speedup vs baseline: 12.5710x; 1.3547x over previous
//
#include <hip/hip_runtime.h>
#include <math.h>

#define DD    64
#define TT    256
#define NROW  4096
#define BLK   512
#define GRID  256          // NROW/16 row-tiles, 1 block/CU, 8 waves = 2/SIMD

typedef __attribute__((ext_vector_type(8))) short  short8;
typedef __attribute__((ext_vector_type(4))) float  f32x4;

__device__ __forceinline__ unsigned short f2bf(float f) {
  unsigned u = __builtin_bit_cast(unsigned, f);
  u += 0x7fffu + ((u >> 16) & 1u);          // round-to-nearest-even
  return (unsigned short)(u >> 16);
}

__device__ __forceinline__ unsigned long long pack4(float4 v) {
  return (unsigned long long)f2bf(v.x)
       | ((unsigned long long)f2bf(v.y) << 16)
       | ((unsigned long long)f2bf(v.z) << 32)
       | ((unsigned long long)f2bf(v.w) << 48);
}

__device__ __forceinline__ short8 load_wfrag(const float* p) {
  float4 a = *(const float4*)p;
  float4 b = *(const float4*)(p + 4);
  short8 r;
  r[0] = (short)f2bf(a.x); r[1] = (short)f2bf(a.y);
  r[2] = (short)f2bf(a.z); r[3] = (short)f2bf(a.w);
  r[4] = (short)f2bf(b.x); r[5] = (short)f2bf(b.y);
  r[6] = (short)f2bf(b.z); r[7] = (short)f2bf(b.w);
  return r;
}

__device__ __forceinline__ float fsigmoid(float x) {
  return __builtin_amdgcn_rcpf(1.0f + __expf(-x));
}
__device__ __forceinline__ float ftanh(float x) {
  return 1.0f - 2.0f * __builtin_amdgcn_rcpf(1.0f + __expf(2.0f * x));
}
// A&S 7.1.26 erf, max abs err 1.5e-7
__device__ __forceinline__ float ferf(float x) {
  float ax = fabsf(x);
  float t  = __builtin_amdgcn_rcpf(fmaf(0.3275911f, ax, 1.0f));
  float p  = fmaf(1.061405429f, t, -1.453152027f);
  p = fmaf(p, t, 1.421413741f);
  p = fmaf(p, t, -0.284496736f);
  p = fmaf(p, t, 0.254829592f);
  p = p * t;
  float y = 1.0f - p * __expf(-ax * ax);
  return copysignf(y, x);
}

// bias_t[t][j] = msg_b[j] + sum_d cos(t*freq[d]+phase[d]) * msg_W[j][128+d]
__global__ void bias_kernel(const float* __restrict__ msg_W,
                            const float* __restrict__ msg_b,
                            const float* __restrict__ freq,
                            const float* __restrict__ phase,
                            float* __restrict__ bias_t) {
  __shared__ float teL[DD];
  const int t = blockIdx.x;
  const int j = threadIdx.x;
  teL[j] = cosf(fmaf((float)t, freq[j], phase[j]));
  __syncthreads();
  float acc = msg_b[j];
  const float* wrow = msg_W + j * 192 + 128;
  #pragma unroll 8
  for (int k = 0; k < DD; ++k) acc = fmaf(teL[k], wrow[k], acc);
  bias_t[t * DD + j] = acc;
}

__launch_bounds__(BLK, 1)
__global__ void scan4(const float* __restrict__ x,
                      const int*   __restrict__ mask,
                      const float* __restrict__ msg_W,
                      const float* __restrict__ W_ih,
                      const float* __restrict__ W_hh,
                      const float* __restrict__ b_ih,
                      const float* __restrict__ b_hh,
                      const float* __restrict__ bias_t,
                      float* __restrict__ out) {
  // bf16 tiles: stride 72 shorts (144 B) -> <=2-way banks on b128 frag reads
  __shared__ alignas(16) unsigned short xs[16 * 72];
  __shared__ alignas(16) unsigned short ss[16 * 72];
  __shared__ alignas(16) unsigned short ms[16 * 72];
  __shared__ alignas(16) float s0a[16 * 68];   // fp32 state staging (gates write, out/init read)
  __shared__ alignas(16) float ghl[16 * 260];  // gh transfer [rr][n*4+{r,z,n,pad}], stride 260 (4-bank rot)
  __shared__ int tr_lds[TT];

  const int tid  = threadIdx.x;
  const int lane = tid & 63;
  const int wv   = tid >> 6;
  const int grp  = wv >> 2;        // 0: compute chain (msg/gi/gates), 1: gh + staging
  const int w4   = wv & 3;
  const int col  = lane & 15;
  const int kh   = lane >> 4;
  const int n    = w4 * 16 + col;  // output column slice this lane owns
  const int row0 = blockIdx.x * 16;

  if (tid < TT) tr_lds[tid] = tid * mask[tid];

  // ---- group-specific weight fragments (registers, one-time) ----
  short8 wm[4], wi[3][2], wh[3][2];
  float bsum01[2] = {0.f, 0.f}, bih2 = 0.f, bhh2 = 0.f;
  if (grp == 0) {
    const float* mrow = msg_W + (size_t)n * 192;
    #pragma unroll
    for (int kf = 0; kf < 4; ++kf) wm[kf] = load_wfrag(mrow + kf * 32 + kh * 8);
    #pragma unroll
    for (int p = 0; p < 3; ++p) {
      const float* irow = W_ih + (size_t)(p * 64 + n) * 64;
      #pragma unroll
      for (int kf = 0; kf < 2; ++kf) wi[p][kf] = load_wfrag(irow + kf * 32 + kh * 8);
    }
    bsum01[0] = b_ih[n]      + b_hh[n];        // r-gate combined bias
    bsum01[1] = b_ih[64 + n] + b_hh[64 + n];   // z-gate combined bias
    bih2 = b_ih[128 + n];
    bhh2 = b_hh[128 + n];
  } else {
    #pragma unroll
    for (int p = 0; p < 3; ++p) {
      const float* hrow = W_hh + (size_t)(p * 64 + n) * 64;
      #pragma unroll
      for (int kf = 0; kf < 2; ++kf) wh[p][kf] = load_wfrag(hrow + kf * 32 + kh * 8);
    }
  }

  // ---- s0 = mean over t (512 threads: 2 time-halves x 16 rows x 16 float4) ----
  {
    const int half = tid >> 8, rem = tid & 255;
    const int fr = rem >> 4, fd = (rem & 15) * 4;
    const float* px = x + ((size_t)half * 128) * (NROW * DD)
                        + (size_t)(row0 + fr) * DD + fd;
    float4 acc = {0.f, 0.f, 0.f, 0.f};
    #pragma unroll 4
    for (int tl = 0; tl < 128; ++tl) {
      float4 v = *(const float4*)(px + (size_t)tl * (NROW * DD));
      acc.x += v.x; acc.y += v.y; acc.z += v.z; acc.w += v.w;
    }
    float* dst = (half == 0) ? &s0a[fr * 68 + fd] : &ghl[fr * 68 + fd];
    *(float4*)dst = acc;
  }
  __syncthreads();
  if (tid < 256) {
    const int fr = tid >> 4, fd = (tid & 15) * 4;
    float4 a = *(const float4*)&s0a[fr * 68 + fd];
    float4 b = *(const float4*)&ghl[fr * 68 + fd];
    const float inv = 1.0f / 256.0f;
    float4 m = { (a.x + b.x) * inv, (a.y + b.y) * inv,
                 (a.z + b.z) * inv, (a.w + b.w) * inv };
    *(float4*)&s0a[fr * 68 + fd] = m;
    *(unsigned long long*)&ss[fr * 72 + fd] = pack4(m);
    float4 xv0 = *(const float4*)(x + (size_t)(row0 + fr) * DD + fd);  // tr[0]=0
    *(unsigned long long*)&xs[fr * 72 + fd] = pack4(xv0);
  }
  __syncthreads();

  // G0: fp32 state registers + first msg bias
  float s_reg[4] = {0.f, 0.f, 0.f, 0.f};
  float btc = 0.f;
  if (grp == 0) {
    #pragma unroll
    for (int i = 0; i < 4; ++i) s_reg[i] = s0a[(kh * 4 + i) * 68 + n];
    btc = bias_t[n];
    __builtin_amdgcn_s_setprio(1);   // critical-chain waves get priority
  }

  // G1 staging map: 256 threads cover 16 rows x 16 float4
  const int t1  = tid & 255;
  const int fr1 = t1 >> 4;
  const int fd1 = (t1 & 15) * 4;
  float4 xv = {0.f, 0.f, 0.f, 0.f};

  for (int t = 0; t < TT; ++t) {
    const int tn = (t + 1 < TT) ? tr_lds[t + 1] : 0;
    if (grp == 0) {
      // ---- msg = GELU([x|s] @ msg_W12^T + bias_t) ----
      const unsigned short* ax = &xs[(lane & 15) * 72];
      const unsigned short* as = &ss[(lane & 15) * 72];
      short8 xa0 = *(const short8*)(ax + kh * 8);
      short8 xa1 = *(const short8*)(ax + 32 + kh * 8);
      short8 sa0 = *(const short8*)(as + kh * 8);
      short8 sa1 = *(const short8*)(as + 32 + kh * 8);
      f32x4 accm = {0.f, 0.f, 0.f, 0.f};
      accm = __builtin_amdgcn_mfma_f32_16x16x32_bf16(xa0, wm[0], accm, 0, 0, 0);
      accm = __builtin_amdgcn_mfma_f32_16x16x32_bf16(xa1, wm[1], accm, 0, 0, 0);
      accm = __builtin_amdgcn_mfma_f32_16x16x32_bf16(sa0, wm[2], accm, 0, 0, 0);
      accm = __builtin_amdgcn_mfma_f32_16x16x32_bf16(sa1, wm[3], accm, 0, 0, 0);
      float btn = 0.f;
      if (t + 1 < TT) btn = bias_t[tn * DD + n];   // prefetch next bias
      #pragma unroll
      for (int i = 0; i < 4; ++i) {
        float a = accm[i] + btc;
        float g = 0.5f * a * (1.0f + ferf(a * 0.70710678118654752f));
        ms[(kh * 4 + i) * 72 + n] = f2bf(g);
      }
      btc = btn;
    } else {
      // ---- gh = s @ W_hh^T (independent of msg) ----
      const unsigned short* as = &ss[(lane & 15) * 72];
      short8 sa0 = *(const short8*)(as + kh * 8);
      short8 sa1 = *(const short8*)(as + 32 + kh * 8);
      f32x4 agh[3];
      #pragma unroll
      for (int p = 0; p < 3; ++p) {
        f32x4 c = {0.f, 0.f, 0.f, 0.f};
        c = __builtin_amdgcn_mfma_f32_16x16x32_bf16(sa0, wh[p][0], c, 0, 0, 0);
        c = __builtin_amdgcn_mfma_f32_16x16x32_bf16(sa1, wh[p][1], c, 0, 0, 0);
        agh[p] = c;
      }
      #pragma unroll
      for (int i = 0; i < 4; ++i) {
        float4 gv = { agh[0][i], agh[1][i], agh[2][i], 0.f };
        *(float4*)&ghl[(kh * 4 + i) * 260 + n * 4] = gv;
      }
      // out-write of t-1 (s0a stable until G0's gates post-B1)
      if (t > 0) {
        float4 ov = *(const float4*)&s0a[fr1 * 68 + fd1];
        *(float4*)(out + ((size_t)(t - 1) * NROW + row0 + fr1) * DD + fd1) = ov;
      }
      // prefetch next x tile
      if (t + 1 < TT)
        xv = *(const float4*)(x + ((size_t)tn * NROW + row0 + fr1) * DD + fd1);
    }
    __syncthreads();  // B1: ms & ghl ready; all xs/ss/s0a reads done

    if (grp == 0) {
      // ---- gi = msg @ W_ih^T, then gates ----
      const unsigned short* am = &ms[(lane & 15) * 72];
      short8 ma0 = *(const short8*)(am + kh * 8);
      short8 ma1 = *(const short8*)(am + 32 + kh * 8);
      f32x4 agi[3];
      #pragma unroll
      for (int p = 0; p < 3; ++p) {
        f32x4 c = {0.f, 0.f, 0.f, 0.f};
        c = __builtin_amdgcn_mfma_f32_16x16x32_bf16(ma0, wi[p][0], c, 0, 0, 0);
        c = __builtin_amdgcn_mfma_f32_16x16x32_bf16(ma1, wi[p][1], c, 0, 0, 0);
        agi[p] = c;
      }
      #pragma unroll
      for (int i = 0; i < 4; ++i) {
        const int rr = kh * 4 + i;
        float4 gh4 = *(const float4*)&ghl[rr * 260 + n * 4];
        float gr  = agi[0][i] + gh4.x + bsum01[0];
        float gz  = agi[1][i] + gh4.y + bsum01[1];
        float gni = agi[2][i] + bih2;
        float gnh = gh4.z + bhh2;
        float rg = fsigmoid(gr);
        float zg = fsigmoid(gz);
        float ng = ftanh(fmaf(rg, gnh, gni));
        float sn = fmaf(zg, s_reg[i] - ng, ng);
        s_reg[i] = sn;
        ss[rr * 72 + n]  = f2bf(sn);
        s0a[rr * 68 + n] = sn;
      }
    } else {
      // stage x(t+1) (xs(t) readers all pre-B1)
      if (t + 1 < TT)
        *(unsigned long long*)&xs[fr1 * 72 + fd1] = pack4(xv);
    }
    __syncthreads();  // B2: ss/s0a/xs updated for next step
  }

  // final output row (t = 255)
  if (grp == 1) {
    float4 ov = *(const float4*)&s0a[fr1 * 68 + fd1];
    *(float4*)(out + ((size_t)(TT - 1) * NROW + row0 + fr1) * DD + fd1) = ov;
  }
}

extern "C" void kernel_launch(void* const* d_in, const int* in_sizes, int n_in,
                              void* d_out, int out_size, void* d_ws, size_t ws_size,
                              hipStream_t stream) {
  const float* x      = (const float*)d_in[0];
  const int*   mask   = (const int*)  d_in[1];
  const float* msg_W  = (const float*)d_in[2];
  const float* msg_b  = (const float*)d_in[3];
  const float* W_ih   = (const float*)d_in[4];
  const float* W_hh   = (const float*)d_in[5];
  const float* b_ih   = (const float*)d_in[6];
  const float* b_hh   = (const float*)d_in[7];
  const float* freq   = (const float*)d_in[8];
  const float* phase  = (const float*)d_in[9];
  float* out    = (float*)d_out;
  float* bias_t = (float*)d_ws;   // TT*DD floats = 64 KB

  (void)in_sizes; (void)n_in; (void)out_size; (void)ws_size;

  bias_kernel<<<TT, DD, 0, stream>>>(msg_W, msg_b, freq, phase, bias_t);
  scan4<<<GRID, BLK, 0, stream>>>(x, mask, msg_W, W_ih, W_hh,
                                  b_ih, b_hh, bias_t, out);
}